// Round 1
// baseline (876.767 us; speedup 1.0000x reference)
//
#include <hip/hip_runtime.h>

// EquivariantProductBasisBlock (MACE-style) for gfx950.
// N=4096 nodes, C=128 channels, irreps in = 0e+1o+2e (dim 9), out = 0e+1o (dim 4).
// Strategy round 0:
//   kernel 1 (cg_setup): port of reference su2_cg/c2r/real_cg in fp64, writes the
//     19 distinct real-CG tensors (1105 floats) into d_ws. Runs every launch
//     (d_ws is re-poisoned before each timed call). ~19 tiny blocks.
//   kernel 2 (epb_main): 1 block per node, 128 threads = channels. CG tables in
//     LDS (uniform broadcast reads), per-thread B[4] via dense small contractions,
//     then channel-mix linear stage via LDS + float4 stores.

#define NN 4096
#define NC 128
#define NE 10
#define NP1 2
#define NP2 9
#define NP3 51
#define CG_TOTAL 1105

// ---------------- CG table metadata (19 distinct (l1,l2,l3) triples) -----------
// idx : triple          size  offset
// 0 (0,0,0) 1    0
// 1 (0,1,1) 9    1
// 2 (0,2,2) 25   10
// 3 (1,0,1) 9    35
// 4 (1,1,0) 9    44
// 5 (1,1,1) 27   53
// 6 (1,1,2) 45   80
// 7 (1,2,1) 45   125
// 8 (1,2,2) 75   170
// 9 (1,2,3) 105  245
// 10 (2,0,2) 25  350
// 11 (2,1,1) 45  375
// 12 (2,1,2) 75  420
// 13 (2,1,3) 105 495
// 14 (2,2,0) 25  600
// 15 (2,2,1) 75  625
// 16 (2,2,2) 125 700
// 17 (2,2,3) 175 825
// 18 (3,2,1) 105 1000   (total 1105)
__device__ const int T_L1[19]  = {0,0,0,1,1,1,1,1,1,1,2,2,2,2,2,2,2,2,3};
__device__ const int T_L2[19]  = {0,1,2,0,1,1,1,2,2,2,0,1,1,1,2,2,2,2,2};
__device__ const int T_L3[19]  = {0,1,2,1,0,1,2,1,2,3,2,1,2,3,0,1,2,3,1};
__device__ const int T_OFF[19] = {0,1,10,35,44,53,80,125,170,245,350,375,420,495,600,625,700,825,1000};

// A-slice offsets per l (l=0 -> [0:1], l=1 -> [1:4], l=2 -> [4:9])
__device__ const int AOFF[3] = {0,1,4};

// PATHS2 = [(0,0,0),(0,1,1),(1,0,1),(1,1,0),(1,1,1),(1,2,1),(2,1,1),(2,2,0),(2,2,1)]
__device__ const int P2_L1[9]  = {0,0,1,1,1,1,2,2,2};
__device__ const int P2_L2[9]  = {0,1,0,1,1,2,1,2,2};
__device__ const int P2_LO[9]  = {0,1,1,0,1,1,1,0,1};
__device__ const int P2_TBL[9] = {0,1,3,4,5,7,11,14,15};

// T12_KEYS (18), in reference order; table idx == key idx (same enumeration).
__device__ const int K_L1[18]  = {0,0,0,1,1,1,1,1,1,1,2,2,2,2,2,2,2,2};
__device__ const int K_L2[18]  = {0,1,2,0,1,1,1,2,2,2,0,1,1,1,2,2,2,2};
__device__ const int K_L12[18] = {0,1,2,1,0,1,2,1,2,3,2,1,2,3,0,1,2,3};

// PATHS3: grouped by key (consecutive), 51 total.
__device__ const int P3_START[19] = {0,2,6,9,13,15,19,22,26,29,30,33,37,40,41,43,47,50,51};
__device__ const int P3_L3[51] = {
  0,1,           // key0 (l12=0)
  0,1,1,2,       // key1 (l12=1)
  1,2,2,         // key2 (l12=2)
  0,1,1,2,       // key3
  0,1,           // key4
  0,1,1,2,       // key5
  1,2,2,         // key6
  0,1,1,2,       // key7
  1,2,2,         // key8
  2,             // key9 (l12=3)
  1,2,2,         // key10
  0,1,1,2,       // key11
  1,2,2,         // key12
  2,             // key13
  0,1,           // key14
  0,1,1,2,       // key15
  1,2,2,         // key16
  2              // key17
};
__device__ const int P3_LO[51] = {
  0,1,
  1,0,1,1,
  1,0,1,
  1,0,1,1,
  0,1,
  1,0,1,1,
  1,0,1,
  1,0,1,1,
  1,0,1,
  1,
  1,0,1,
  1,0,1,1,
  1,0,1,
  1,
  0,1,
  1,0,1,1,
  1,0,1,
  1
};
__device__ const int P3_TBL[51] = {
  0,1,
  3,4,5,7,
  11,14,15,
  3,4,5,7,
  0,1,
  3,4,5,7,
  11,14,15,
  3,4,5,7,
  11,14,15,
  18,
  11,14,15,
  3,4,5,7,
  11,14,15,
  18,
  0,1,
  3,4,5,7,
  11,14,15,
  18
};

// ------------------------- setup kernel: compute real CG -----------------------
__device__ const double FACT[9] = {1.,1.,2.,6.,24.,120.,720.,5040.,40320.};

struct cplx { double re, im; };
__device__ inline cplx cmul(cplx a, cplx b) {
  return { a.re*b.re - a.im*b.im, a.re*b.im + a.im*b.re };
}

__device__ double su2_cg(int j1,int m1,int j2,int m2,int j3,int m3) {
  if (m3 != m1 + m2) return 0.0;
  int vmin = -j1 + j2 + m3; if (-j1 + m1 > vmin) vmin = -j1 + m1; if (0 > vmin) vmin = 0;
  int vmax = j2 + j3 + m1; if (j3 - j1 + j2 < vmax) vmax = j3 - j1 + j2; if (j3 + m3 < vmax) vmax = j3 + m3;
  double C = sqrt((2.0*j3 + 1.0)
                  * FACT[j3 + j1 - j2] * FACT[j3 - j1 + j2] * FACT[j1 + j2 - j3]
                  * FACT[j3 + m3] * FACT[j3 - m3]
                  / (FACT[j1 + j2 + j3 + 1] * FACT[j1 - m1] * FACT[j1 + m1]
                     * FACT[j2 - m2] * FACT[j2 + m2]));
  double S = 0.0;
  for (int v = vmin; v <= vmax; ++v) {
    double sgn = ((v + j2 + m2) & 1) ? -1.0 : 1.0;
    S += sgn * FACT[j2 + j3 + m1 - v] * FACT[j1 - m1 + v]
         / (FACT[v] * FACT[j3 - j1 + j2 - v] * FACT[j3 + m3 - v] * FACT[v + j1 - j2 - m3]);
  }
  return C * S;
}

// entry (row r, col c) of (-1j)^l * q(l), q = real->complex SH change of basis
__device__ cplx c2r_entry(int l, int r, int c) {
  const double is2 = 0.70710678118654752440;  // 1/sqrt(2)
  int m = r - l;
  cplx v = {0.0, 0.0};
  if (m < 0) {
    if (c == l - m)       v = { is2, 0.0 };     // col l+|m|
    else if (c == l + m)  v = { 0.0, -is2 };    // col l-|m|: -1j/sqrt2
  } else if (m == 0) {
    if (c == l)           v = { 1.0, 0.0 };
  } else {
    double sgn = (m & 1) ? -1.0 : 1.0;
    if (c == l + m)       v = { sgn * is2, 0.0 };
    else if (c == l - m)  v = { 0.0, sgn * is2 };
  }
  // multiply by (-i)^l
  int ph = l & 3;
  cplx o;
  if (ph == 0)      o = v;
  else if (ph == 1) o = {  v.im, -v.re };  // * (-i)
  else if (ph == 2) o = { -v.re, -v.im };  // * (-1)
  else              o = { -v.im,  v.re };  // * (+i)
  return o;
}

__global__ void cg_setup(float* __restrict__ cg) {
  __shared__ double Cc[175];
  const int t = blockIdx.x;
  const int l1 = T_L1[t], l2 = T_L2[t], l3 = T_L3[t], off = T_OFF[t];
  const int d1 = 2*l1+1, d2 = 2*l2+1, d3 = 2*l3+1;
  const int sz = d1*d2*d3;
  for (int e = threadIdx.x; e < sz; e += blockDim.x) {
    int i = e / (d2*d3); int rr = e % (d2*d3); int k = rr / d3, n = rr % d3;
    Cc[e] = su2_cg(l1, i - l1, l2, k - l2, l3, n - l3);
  }
  __syncthreads();
  // R[j,l,m] = sum_{i,k,n} Q1[i,j] Q2[k,l] conj(Q3[n,m]) Cc[i,k,n]; keep real part
  for (int e = threadIdx.x; e < sz; e += blockDim.x) {
    int j = e / (d2*d3); int rr = e % (d2*d3); int l = rr / d3, m = rr % d3;
    double acc = 0.0;
    for (int i = 0; i < d1; ++i) {
      cplx q1 = c2r_entry(l1, i, j);
      if (q1.re == 0.0 && q1.im == 0.0) continue;
      for (int k = 0; k < d2; ++k) {
        cplx q2 = c2r_entry(l2, k, l);
        if (q2.re == 0.0 && q2.im == 0.0) continue;
        cplx q12 = cmul(q1, q2);
        for (int n = 0; n < d3; ++n) {
          double cc = Cc[(i*d2 + k)*d3 + n];
          if (cc == 0.0) continue;
          cplx q3 = c2r_entry(l3, n, m);
          // Re(q12 * conj(q3)) * cc
          acc += (q12.re*q3.re + q12.im*q3.im) * cc;
        }
      }
    }
    cg[off + e] = (float)acc;
  }
}

// ------------------------------- main kernel -----------------------------------
__global__ __launch_bounds__(128) void epb_main(
    const float* __restrict__ nf,   // [N, C, 9]
    const float* __restrict__ w1,   // [E, 2, C]
    const float* __restrict__ w2,   // [E, 9, C]
    const float* __restrict__ w3,   // [E, 51, C]
    const float* __restrict__ lw0,  // [C, F=128]
    const float* __restrict__ lw1,  // [C, F=128]
    const int*   __restrict__ species, // [N]
    const float* __restrict__ cg_g, // [1105]
    float* __restrict__ out)        // [N, F, 4]
{
  __shared__ float cg[CG_TOTAL];
  __shared__ float4 Bsh[NC];
  const int n = blockIdx.x, c = threadIdx.x;
  for (int e = c; e < CG_TOTAL; e += NC) cg[e] = cg_g[e];
  const int s = species[n];

  float A[9];
  const float* ap = nf + (size_t)(n*NC + c) * 9;
  #pragma unroll
  for (int i = 0; i < 9; ++i) A[i] = ap[i];
  __syncthreads();

  float B[4] = {0.f, 0.f, 0.f, 0.f};  // B[0]=0e ; B[1..3]=1o

  // ---- order 1: PATHS1 = [lo=0, lo=1]
  {
    float w10 = w1[(s*NP1 + 0)*NC + c];
    float w11 = w1[(s*NP1 + 1)*NC + c];
    B[0] += w10 * A[0];
    B[1] += w11 * A[1];
    B[2] += w11 * A[2];
    B[3] += w11 * A[3];
  }

  // ---- order 2
  for (int p = 0; p < NP2; ++p) {
    int l1 = P2_L1[p], l2 = P2_L2[p], lo = P2_LO[p];
    int d1 = 2*l1+1, d2 = 2*l2+1, dl = 2*lo+1;
    const float* cgt = cg + T_OFF[P2_TBL[p]];
    const float* A1 = A + AOFF[l1];
    const float* A2 = A + AOFF[l2];
    float w = w2[(s*NP2 + p)*NC + c];
    for (int k = 0; k < dl; ++k) {
      float v = 0.f;
      for (int i = 0; i < d1; ++i)
        for (int j = 0; j < d2; ++j)
          v += cgt[(i*d2 + j)*dl + k] * A1[i] * A2[j];
      B[lo + k] += w * v;
    }
  }

  // ---- order 3: per T12 key, build tt then consume its paths
  for (int t = 0; t < 18; ++t) {
    int l1 = K_L1[t], l2 = K_L2[t], l12 = K_L12[t];
    int d1 = 2*l1+1, d2 = 2*l2+1, d12 = 2*l12+1;
    const float* cgt = cg + T_OFF[t];
    const float* A1 = A + AOFF[l1];
    const float* A2 = A + AOFF[l2];
    float tt[7];
    for (int k = 0; k < d12; ++k) {
      float v = 0.f;
      for (int i = 0; i < d1; ++i)
        for (int j = 0; j < d2; ++j)
          v += cgt[(i*d2 + j)*d12 + k] * A1[i] * A2[j];
      tt[k] = v;
    }
    for (int p = P3_START[t]; p < P3_START[t+1]; ++p) {
      int l3 = P3_L3[p], lo = P3_LO[p];
      int d3 = 2*l3+1, dl = 2*lo+1;
      const float* cg2 = cg + T_OFF[P3_TBL[p]];
      const float* A3 = A + AOFF[l3];
      float w = w3[(s*NP3 + p)*NC + c];
      for (int m = 0; m < dl; ++m) {
        float v = 0.f;
        for (int k = 0; k < d12; ++k)
          for (int j = 0; j < d3; ++j)
            v += cg2[(k*d3 + j)*dl + m] * tt[k] * A3[j];
        B[lo + m] += w * v;
      }
    }
  }

  Bsh[c] = make_float4(B[0], B[1], B[2], B[3]);
  __syncthreads();

  // ---- equivariant linear: out[n,f,0]=sum_c B0*lw0 ; out[n,f,1..3]=sum_c B1*lw1
  const float scale = 0.08838834764831845f;  // 1/sqrt(128)
  const int f = c;
  float o0 = 0.f, o1 = 0.f, o2 = 0.f, o3 = 0.f;
  for (int ch = 0; ch < NC; ++ch) {
    float4 b = Bsh[ch];                 // uniform address -> LDS broadcast, free
    float wa = lw0[ch*NC + f];          // coalesced across f
    float wb = lw1[ch*NC + f];
    o0 += b.x * wa;
    o1 += b.y * wb;
    o2 += b.z * wb;
    o3 += b.w * wb;
  }
  float4 r = make_float4(o0*scale, o1*scale, o2*scale, o3*scale);
  *reinterpret_cast<float4*>(out + (size_t)(n*NC + f) * 4) = r;
}

// ------------------------------- launcher --------------------------------------
extern "C" void kernel_launch(void* const* d_in, const int* in_sizes, int n_in,
                              void* d_out, int out_size, void* d_ws, size_t ws_size,
                              hipStream_t stream) {
  const float* nf  = (const float*)d_in[0];
  const float* w1  = (const float*)d_in[1];
  const float* w2  = (const float*)d_in[2];
  const float* w3  = (const float*)d_in[3];
  const float* lw0 = (const float*)d_in[4];
  const float* lw1 = (const float*)d_in[5];
  const int*   spc = (const int*)  d_in[6];
  float* out = (float*)d_out;
  float* cg  = (float*)d_ws;   // 1105 floats, rebuilt every launch

  hipLaunchKernelGGL(cg_setup, dim3(19), dim3(256), 0, stream, cg);
  hipLaunchKernelGGL(epb_main, dim3(NN), dim3(NC), 0, stream,
                     nf, w1, w2, w3, lw0, lw1, spc, cg, out);
}

// Round 2
// 108.150 us; speedup vs baseline: 8.1070x; 8.1070x over previous
//
#include <hip/hip_runtime.h>
#include <utility>

// EquivariantProductBasisBlock (MACE-style) for gfx950 — round 2.
// All CG tables computed at COMPILE TIME (constexpr port of su2_cg/c2r/real_cg).
// Product basis fully unrolled via static_for; zero coefficients eliminated with
// `if constexpr`; coefficients become instruction immediates. No setup kernel,
// no cg LDS, no metadata loads. One block (128 thr) per node; channel = tid.

#define NN 4096
#define NC 128

// ---------------------------- static_for ---------------------------------------
template<typename F, int... Is>
__device__ __forceinline__ void sfor_impl(F&& f, std::integer_sequence<int, Is...>) {
  (f(std::integral_constant<int, Is>{}), ...);
}
template<int N, typename F>
__device__ __forceinline__ void sfor(F&& f) {
  sfor_impl((F&&)f, std::make_integer_sequence<int, N>{});
}

// ---------------------------- CG metadata (constexpr) --------------------------
constexpr int T_L1c[19]  = {0,0,0,1,1,1,1,1,1,1,2,2,2,2,2,2,2,2,3};
constexpr int T_L2c[19]  = {0,1,2,0,1,1,1,2,2,2,0,1,1,1,2,2,2,2,2};
constexpr int T_L3c[19]  = {0,1,2,1,0,1,2,1,2,3,2,1,2,3,0,1,2,3,1};
constexpr int T_OFFc[19] = {0,1,10,35,44,53,80,125,170,245,350,375,420,495,600,625,700,825,1000};
constexpr int AOFFc[3]   = {0,1,4};

constexpr int P2_L1c[9]  = {0,0,1,1,1,1,2,2,2};
constexpr int P2_L2c[9]  = {0,1,0,1,1,2,1,2,2};
constexpr int P2_LOc[9]  = {0,1,1,0,1,1,1,0,1};
constexpr int P2_TBLc[9] = {0,1,3,4,5,7,11,14,15};

constexpr int K_L1c[18]  = {0,0,0,1,1,1,1,1,1,1,2,2,2,2,2,2,2,2};
constexpr int K_L2c[18]  = {0,1,2,0,1,1,1,2,2,2,0,1,1,1,2,2,2,2};
constexpr int K_L12c[18] = {0,1,2,1,0,1,2,1,2,3,2,1,2,3,0,1,2,3};

constexpr int P3_STARTc[19] = {0,2,6,9,13,15,19,22,26,29,30,33,37,40,41,43,47,50,51};
constexpr int P3_L3c[51] = {
  0,1,  0,1,1,2,  1,2,2,  0,1,1,2,  0,1,  0,1,1,2,  1,2,2,  0,1,1,2,  1,2,2,
  2,  1,2,2,  0,1,1,2,  1,2,2,  2,  0,1,  0,1,1,2,  1,2,2,  2 };
constexpr int P3_LOc[51] = {
  0,1,  1,0,1,1,  1,0,1,  1,0,1,1,  0,1,  1,0,1,1,  1,0,1,  1,0,1,1,  1,0,1,
  1,  1,0,1,  1,0,1,1,  1,0,1,  1,  0,1,  1,0,1,1,  1,0,1,  1 };
constexpr int P3_TBLc[51] = {
  0,1,  3,4,5,7,  11,14,15,  3,4,5,7,  0,1,  3,4,5,7,  11,14,15,  3,4,5,7,
  11,14,15,  18,  11,14,15,  3,4,5,7,  11,14,15,  18,  0,1,  3,4,5,7,
  11,14,15,  18 };

// ---------------------------- constexpr CG computation -------------------------
constexpr double cfact(int n) { double r = 1.0; for (int i = 2; i <= n; ++i) r *= i; return r; }
constexpr double csqrt(double x) {
  if (x <= 0.0) return 0.0;
  double r = x > 1.0 ? x : 1.0;
  for (int i = 0; i < 64; ++i) r = 0.5 * (r + x / r);
  return r;
}
constexpr double su2cg(int j1, int m1, int j2, int m2, int j3, int m3) {
  if (m3 != m1 + m2) return 0.0;
  int vmin = -j1 + j2 + m3; if (-j1 + m1 > vmin) vmin = -j1 + m1; if (vmin < 0) vmin = 0;
  int vmax = j2 + j3 + m1; if (j3 - j1 + j2 < vmax) vmax = j3 - j1 + j2; if (j3 + m3 < vmax) vmax = j3 + m3;
  double C = csqrt((2.0 * j3 + 1.0)
                   * cfact(j3 + j1 - j2) * cfact(j3 - j1 + j2) * cfact(j1 + j2 - j3)
                   * cfact(j3 + m3) * cfact(j3 - m3)
                   / (cfact(j1 + j2 + j3 + 1) * cfact(j1 - m1) * cfact(j1 + m1)
                      * cfact(j2 - m2) * cfact(j2 + m2)));
  double S = 0.0;
  for (int v = vmin; v <= vmax; ++v) {
    double sgn = ((v + j2 + m2) & 1) ? -1.0 : 1.0;
    S += sgn * cfact(j2 + j3 + m1 - v) * cfact(j1 - m1 + v)
         / (cfact(v) * cfact(j3 - j1 + j2 - v) * cfact(j3 + m3 - v) * cfact(v + j1 - j2 - m3));
  }
  return C * S;
}

struct Cx { double re, im; };
constexpr Cx cxmul(Cx a, Cx b) { return Cx{a.re * b.re - a.im * b.im, a.re * b.im + a.im * b.re}; }
struct Row { int cnt; int col[2]; Cx v[2]; };

// row r of (-1j)^l * q(l)  (q = real->complex SH basis change, e3nn convention)
constexpr Row c2r_row(int l, int r) {
  Row out{0, {0, 0}, {{0, 0}, {0, 0}}};
  constexpr double is2 = 0.70710678118654752440;
  const int m = r - l;
  if (m < 0) {
    out.cnt = 2;
    out.col[0] = l - m; out.v[0] = Cx{is2, 0.0};
    out.col[1] = l + m; out.v[1] = Cx{0.0, -is2};
  } else if (m == 0) {
    out.cnt = 1; out.col[0] = l; out.v[0] = Cx{1.0, 0.0};
  } else {
    const double sgn = (m & 1) ? -1.0 : 1.0;
    out.cnt = 2;
    out.col[0] = l + m; out.v[0] = Cx{sgn * is2, 0.0};
    out.col[1] = l - m; out.v[1] = Cx{0.0, sgn * is2};
  }
  const int ph = l & 3;
  for (int a = 0; a < out.cnt; ++a) {
    Cx v = out.v[a];
    out.v[a] = (ph == 0) ? v
             : (ph == 1) ? Cx{v.im, -v.re}     // * (-i)
             : (ph == 2) ? Cx{-v.re, -v.im}    // * (-1)
                         : Cx{-v.im, v.re};    // * (+i)
  }
  return out;
}

struct CGAll { float v[1105]; };
constexpr CGAll make_cg() {
  CGAll R{};
  for (int t = 0; t < 19; ++t) {
    const int l1 = T_L1c[t], l2 = T_L2c[t], l3 = T_L3c[t], off = T_OFFc[t];
    const int d1 = 2 * l1 + 1, d2 = 2 * l2 + 1, d3 = 2 * l3 + 1;
    double tmp[175] = {};
    for (int i = 0; i < d1; ++i) {
      const int m1 = i - l1;
      const Row r1 = c2r_row(l1, i);
      for (int k = 0; k < d2; ++k) {
        const int m2 = k - l2, m3 = m1 + m2;
        if (m3 < -l3 || m3 > l3) continue;
        const double cc = su2cg(l1, m1, l2, m2, l3, m3);
        if (cc == 0.0) continue;
        const Row r2 = c2r_row(l2, k);
        const Row r3 = c2r_row(l3, m3 + l3);
        for (int a = 0; a < r1.cnt; ++a)
          for (int b = 0; b < r2.cnt; ++b) {
            const Cx q12 = cxmul(r1.v[a], r2.v[b]);
            for (int cdx = 0; cdx < r3.cnt; ++cdx) {
              // Re(q12 * conj(q3)) * cc  scattered into R[j, l, m]
              const double re = q12.re * r3.v[cdx].re + q12.im * r3.v[cdx].im;
              tmp[(r1.col[a] * d2 + r2.col[b]) * d3 + r3.col[cdx]] += re * cc;
            }
          }
      }
    }
    const int sz = d1 * d2 * d3;
    for (int e = 0; e < sz; ++e) R.v[off + e] = (float)tmp[e];
  }
  return R;
}
constexpr CGAll CG_ALL = make_cg();

// ------------------------------- main kernel -----------------------------------
__global__ __launch_bounds__(128) void epb_main(
    const float* __restrict__ nf,      // [N, C, 9]
    const float* __restrict__ w1,      // [E, 2, C]
    const float* __restrict__ w2,      // [E, 9, C]
    const float* __restrict__ w3,      // [E, 51, C]
    const float* __restrict__ lw0,     // [C, F=128]
    const float* __restrict__ lw1,     // [C, F=128]
    const int*   __restrict__ species, // [N]
    float* __restrict__ out)           // [N, F, 4]
{
  __shared__ float4 Anf4[288];              // 128*9 floats, staged as float4
  __shared__ float4 Bsh[NC];
  const int n = blockIdx.x, c = threadIdx.x;

  // coalesced float4 staging of this node's 128x9 block (start is 16B-aligned)
  const float4* src = reinterpret_cast<const float4*>(nf + (size_t)n * (NC * 9));
  Anf4[c]       = src[c];
  Anf4[c + 128] = src[c + 128];
  if (c < 32) Anf4[c + 256] = src[c + 256];
  const int s = species[n];
  __syncthreads();

  const float* Anf = reinterpret_cast<const float*>(Anf4);
  float A[9];
  #pragma unroll
  for (int i = 0; i < 9; ++i) A[i] = Anf[c * 9 + i];  // stride 9: 2-way alias, free

  const float* w1p = w1 + (size_t)s * 2 * NC + c;
  const float* w2p = w2 + (size_t)s * 9 * NC + c;
  const float* w3p = w3 + (size_t)s * 51 * NC + c;

  float B[4] = {0.f, 0.f, 0.f, 0.f};  // B[0]=0e ; B[1..3]=1o

  // ---- order 1
  {
    const float w10 = w1p[0];
    const float w11 = w1p[NC];
    B[0] = fmaf(w10, A[0], B[0]);
    B[1] = fmaf(w11, A[1], B[1]);
    B[2] = fmaf(w11, A[2], B[2]);
    B[3] = fmaf(w11, A[3], B[3]);
  }

  // ---- order 2 (fully unrolled, constants inlined, zeros eliminated)
  sfor<9>([&](auto P) {
    constexpr int p  = P.value;
    constexpr int l1 = P2_L1c[p], l2 = P2_L2c[p], lo = P2_LOc[p];
    constexpr int d1 = 2 * l1 + 1, d2 = 2 * l2 + 1, dl = 2 * lo + 1;
    constexpr int off = T_OFFc[P2_TBLc[p]];
    const float w = w2p[p * NC];
    sfor<dl>([&](auto Kk) {
      constexpr int k = Kk.value;
      float v = 0.f;
      sfor<d1>([&](auto I) {
        sfor<d2>([&](auto J) {
          constexpr float cgc = CG_ALL.v[off + (I.value * d2 + J.value) * dl + k];
          if constexpr (cgc != 0.0f) {
            constexpr int ia = AOFFc[l1] + I.value, ja = AOFFc[l2] + J.value;
            constexpr int x = ia < ja ? ia : ja, y = ia < ja ? ja : ia;  // canonical for CSE
            v = fmaf(cgc, A[x] * A[y], v);
          }
        });
      });
      B[lo + k] = fmaf(w, v, B[lo + k]);
    });
  });

  // ---- order 3: per T12 key, build tt (sparse, immediates) then consume paths
  sfor<18>([&](auto T) {
    constexpr int t   = T.value;
    constexpr int l1  = K_L1c[t], l2 = K_L2c[t], l12 = K_L12c[t];
    constexpr int d1  = 2 * l1 + 1, d2 = 2 * l2 + 1, d12 = 2 * l12 + 1;
    constexpr int off = T_OFFc[t];
    float tt[d12];
    sfor<d12>([&](auto Kk) {
      constexpr int k = Kk.value;
      float v = 0.f;
      sfor<d1>([&](auto I) {
        sfor<d2>([&](auto J) {
          constexpr float cgc = CG_ALL.v[off + (I.value * d2 + J.value) * d12 + k];
          if constexpr (cgc != 0.0f) {
            constexpr int ia = AOFFc[l1] + I.value, ja = AOFFc[l2] + J.value;
            constexpr int x = ia < ja ? ia : ja, y = ia < ja ? ja : ia;
            v = fmaf(cgc, A[x] * A[y], v);
          }
        });
      });
      tt[k] = v;
    });
    constexpr int pcnt = P3_STARTc[t + 1] - P3_STARTc[t];
    sfor<pcnt>([&](auto PP) {
      constexpr int p  = P3_STARTc[t] + PP.value;
      constexpr int l3 = P3_L3c[p], lo = P3_LOc[p];
      constexpr int d3 = 2 * l3 + 1, dl = 2 * lo + 1;
      constexpr int off2 = T_OFFc[P3_TBLc[p]];
      const float w = w3p[p * NC];
      sfor<dl>([&](auto M) {
        float v = 0.f;
        sfor<d12>([&](auto Kk) {
          sfor<d3>([&](auto J) {
            constexpr float cgc = CG_ALL.v[off2 + (Kk.value * d3 + J.value) * dl + M.value];
            if constexpr (cgc != 0.0f)
              v = fmaf(cgc, tt[Kk.value] * A[AOFFc[l3] + J.value], v);  // product CSE'd
          });
        });
        B[lo + M.value] = fmaf(w, v, B[lo + M.value]);
      });
    });
  });

  Bsh[c] = make_float4(B[0], B[1], B[2], B[3]);
  __syncthreads();

  // ---- equivariant linear (per-node rank-128 mix), coalesced weight reads
  const float scale = 0.08838834764831845f;  // 1/sqrt(128)
  const float* lw0p = lw0 + c;
  const float* lw1p = lw1 + c;
  float o0 = 0.f, o1 = 0.f, o2 = 0.f, o3 = 0.f;
  #pragma unroll 16
  for (int ch = 0; ch < NC; ++ch) {
    const float4 b = Bsh[ch];          // uniform address -> LDS broadcast
    const float wa = lw0p[ch * NC];    // coalesced across f=c
    const float wb = lw1p[ch * NC];
    o0 = fmaf(b.x, wa, o0);
    o1 = fmaf(b.y, wb, o1);
    o2 = fmaf(b.z, wb, o2);
    o3 = fmaf(b.w, wb, o3);
  }
  const float4 r = make_float4(o0 * scale, o1 * scale, o2 * scale, o3 * scale);
  *reinterpret_cast<float4*>(out + (size_t)(n * NC + c) * 4) = r;
}

// ------------------------------- launcher --------------------------------------
extern "C" void kernel_launch(void* const* d_in, const int* in_sizes, int n_in,
                              void* d_out, int out_size, void* d_ws, size_t ws_size,
                              hipStream_t stream) {
  const float* nf  = (const float*)d_in[0];
  const float* w1  = (const float*)d_in[1];
  const float* w2  = (const float*)d_in[2];
  const float* w3  = (const float*)d_in[3];
  const float* lw0 = (const float*)d_in[4];
  const float* lw1 = (const float*)d_in[5];
  const int*   spc = (const int*)  d_in[6];
  float* out = (float*)d_out;
  (void)d_ws; (void)ws_size; (void)in_sizes; (void)n_in; (void)out_size;

  hipLaunchKernelGGL(epb_main, dim3(NN), dim3(NC), 0, stream,
                     nf, w1, w2, w3, lw0, lw1, spc, out);
}

// Round 3
// 107.624 us; speedup vs baseline: 8.1466x; 1.0049x over previous
//
#include <hip/hip_runtime.h>
#include <utility>

// EquivariantProductBasisBlock (MACE-style) for gfx950 — round 3.
// Round-2 learned: linear stage streamed 128KB of weights per wave (1 GB L2
// traffic) -> stall-bound at VALUBusy 38%. Round 3: node-tiled fused kernel.
// Block = 256 threads, TN=8 nodes. Basis: 4 (node,channel) pairs per thread
// (runtime loop, one code instance). Linear: 2 features x 2 nodes per thread,
// 4x weight-traffic reduction (-> ~260 MB L2) + LDS broadcast B reads.

#define NN 4096
#define NC 128
#define TN 8

// ---------------------------- static_for ---------------------------------------
template<typename F, int... Is>
__device__ __forceinline__ void sfor_impl(F&& f, std::integer_sequence<int, Is...>) {
  (f(std::integral_constant<int, Is>{}), ...);
}
template<int N, typename F>
__device__ __forceinline__ void sfor(F&& f) {
  sfor_impl((F&&)f, std::make_integer_sequence<int, N>{});
}

// ---------------------------- CG metadata (constexpr) --------------------------
constexpr int T_L1c[19]  = {0,0,0,1,1,1,1,1,1,1,2,2,2,2,2,2,2,2,3};
constexpr int T_L2c[19]  = {0,1,2,0,1,1,1,2,2,2,0,1,1,1,2,2,2,2,2};
constexpr int T_L3c[19]  = {0,1,2,1,0,1,2,1,2,3,2,1,2,3,0,1,2,3,1};
constexpr int T_OFFc[19] = {0,1,10,35,44,53,80,125,170,245,350,375,420,495,600,625,700,825,1000};
constexpr int AOFFc[3]   = {0,1,4};

constexpr int P2_L1c[9]  = {0,0,1,1,1,1,2,2,2};
constexpr int P2_L2c[9]  = {0,1,0,1,1,2,1,2,2};
constexpr int P2_LOc[9]  = {0,1,1,0,1,1,1,0,1};
constexpr int P2_TBLc[9] = {0,1,3,4,5,7,11,14,15};

constexpr int K_L1c[18]  = {0,0,0,1,1,1,1,1,1,1,2,2,2,2,2,2,2,2};
constexpr int K_L2c[18]  = {0,1,2,0,1,1,1,2,2,2,0,1,1,1,2,2,2,2};
constexpr int K_L12c[18] = {0,1,2,1,0,1,2,1,2,3,2,1,2,3,0,1,2,3};

constexpr int P3_STARTc[19] = {0,2,6,9,13,15,19,22,26,29,30,33,37,40,41,43,47,50,51};
constexpr int P3_L3c[51] = {
  0,1,  0,1,1,2,  1,2,2,  0,1,1,2,  0,1,  0,1,1,2,  1,2,2,  0,1,1,2,  1,2,2,
  2,  1,2,2,  0,1,1,2,  1,2,2,  2,  0,1,  0,1,1,2,  1,2,2,  2 };
constexpr int P3_LOc[51] = {
  0,1,  1,0,1,1,  1,0,1,  1,0,1,1,  0,1,  1,0,1,1,  1,0,1,  1,0,1,1,  1,0,1,
  1,  1,0,1,  1,0,1,1,  1,0,1,  1,  0,1,  1,0,1,1,  1,0,1,  1 };
constexpr int P3_TBLc[51] = {
  0,1,  3,4,5,7,  11,14,15,  3,4,5,7,  0,1,  3,4,5,7,  11,14,15,  3,4,5,7,
  11,14,15,  18,  11,14,15,  3,4,5,7,  11,14,15,  18,  0,1,  3,4,5,7,
  11,14,15,  18 };

// ---------------------------- constexpr CG computation -------------------------
constexpr double cfact(int n) { double r = 1.0; for (int i = 2; i <= n; ++i) r *= i; return r; }
constexpr double csqrt(double x) {
  if (x <= 0.0) return 0.0;
  double r = x > 1.0 ? x : 1.0;
  for (int i = 0; i < 64; ++i) r = 0.5 * (r + x / r);
  return r;
}
constexpr double su2cg(int j1, int m1, int j2, int m2, int j3, int m3) {
  if (m3 != m1 + m2) return 0.0;
  int vmin = -j1 + j2 + m3; if (-j1 + m1 > vmin) vmin = -j1 + m1; if (vmin < 0) vmin = 0;
  int vmax = j2 + j3 + m1; if (j3 - j1 + j2 < vmax) vmax = j3 - j1 + j2; if (j3 + m3 < vmax) vmax = j3 + m3;
  double C = csqrt((2.0 * j3 + 1.0)
                   * cfact(j3 + j1 - j2) * cfact(j3 - j1 + j2) * cfact(j1 + j2 - j3)
                   * cfact(j3 + m3) * cfact(j3 - m3)
                   / (cfact(j1 + j2 + j3 + 1) * cfact(j1 - m1) * cfact(j1 + m1)
                      * cfact(j2 - m2) * cfact(j2 + m2)));
  double S = 0.0;
  for (int v = vmin; v <= vmax; ++v) {
    double sgn = ((v + j2 + m2) & 1) ? -1.0 : 1.0;
    S += sgn * cfact(j2 + j3 + m1 - v) * cfact(j1 - m1 + v)
         / (cfact(v) * cfact(j3 - j1 + j2 - v) * cfact(j3 + m3 - v) * cfact(v + j1 - j2 - m3));
  }
  return C * S;
}

struct Cx { double re, im; };
constexpr Cx cxmul(Cx a, Cx b) { return Cx{a.re * b.re - a.im * b.im, a.re * b.im + a.im * b.re}; }
struct Row { int cnt; int col[2]; Cx v[2]; };

constexpr Row c2r_row(int l, int r) {
  Row out{0, {0, 0}, {{0, 0}, {0, 0}}};
  constexpr double is2 = 0.70710678118654752440;
  const int m = r - l;
  if (m < 0) {
    out.cnt = 2;
    out.col[0] = l - m; out.v[0] = Cx{is2, 0.0};
    out.col[1] = l + m; out.v[1] = Cx{0.0, -is2};
  } else if (m == 0) {
    out.cnt = 1; out.col[0] = l; out.v[0] = Cx{1.0, 0.0};
  } else {
    const double sgn = (m & 1) ? -1.0 : 1.0;
    out.cnt = 2;
    out.col[0] = l + m; out.v[0] = Cx{sgn * is2, 0.0};
    out.col[1] = l - m; out.v[1] = Cx{0.0, sgn * is2};
  }
  const int ph = l & 3;
  for (int a = 0; a < out.cnt; ++a) {
    Cx v = out.v[a];
    out.v[a] = (ph == 0) ? v
             : (ph == 1) ? Cx{v.im, -v.re}
             : (ph == 2) ? Cx{-v.re, -v.im}
                         : Cx{-v.im, v.re};
  }
  return out;
}

struct CGAll { float v[1105]; };
constexpr CGAll make_cg() {
  CGAll R{};
  for (int t = 0; t < 19; ++t) {
    const int l1 = T_L1c[t], l2 = T_L2c[t], l3 = T_L3c[t], off = T_OFFc[t];
    const int d1 = 2 * l1 + 1, d2 = 2 * l2 + 1, d3 = 2 * l3 + 1;
    double tmp[175] = {};
    for (int i = 0; i < d1; ++i) {
      const int m1 = i - l1;
      const Row r1 = c2r_row(l1, i);
      for (int k = 0; k < d2; ++k) {
        const int m2 = k - l2, m3 = m1 + m2;
        if (m3 < -l3 || m3 > l3) continue;
        const double cc = su2cg(l1, m1, l2, m2, l3, m3);
        if (cc == 0.0) continue;
        const Row r2 = c2r_row(l2, k);
        const Row r3 = c2r_row(l3, m3 + l3);
        for (int a = 0; a < r1.cnt; ++a)
          for (int b = 0; b < r2.cnt; ++b) {
            const Cx q12 = cxmul(r1.v[a], r2.v[b]);
            for (int cdx = 0; cdx < r3.cnt; ++cdx) {
              const double re = q12.re * r3.v[cdx].re + q12.im * r3.v[cdx].im;
              tmp[(r1.col[a] * d2 + r2.col[b]) * d3 + r3.col[cdx]] += re * cc;
            }
          }
      }
    }
    const int sz = d1 * d2 * d3;
    for (int e = 0; e < sz; ++e) R.v[off + e] = (float)tmp[e];
  }
  return R;
}
constexpr CGAll CG_ALL = make_cg();

// ------------------------- basis for one (node,channel) pair -------------------
__device__ __forceinline__ void basis_pair(
    const float* __restrict__ Ap,      // 9 floats (LDS)
    const float* __restrict__ w1p,     // stride NC between paths
    const float* __restrict__ w2p,
    const float* __restrict__ w3p,
    float B[4])
{
  float A[9];
  #pragma unroll
  for (int i = 0; i < 9; ++i) A[i] = Ap[i];

  B[0] = B[1] = B[2] = B[3] = 0.f;

  // ---- order 1
  {
    const float w10 = w1p[0];
    const float w11 = w1p[NC];
    B[0] = fmaf(w10, A[0], B[0]);
    B[1] = fmaf(w11, A[1], B[1]);
    B[2] = fmaf(w11, A[2], B[2]);
    B[3] = fmaf(w11, A[3], B[3]);
  }

  // ---- order 2
  sfor<9>([&](auto P) {
    constexpr int p  = P.value;
    constexpr int l1 = P2_L1c[p], l2 = P2_L2c[p], lo = P2_LOc[p];
    constexpr int d1 = 2 * l1 + 1, d2 = 2 * l2 + 1, dl = 2 * lo + 1;
    constexpr int off = T_OFFc[P2_TBLc[p]];
    const float w = w2p[p * NC];
    sfor<dl>([&](auto Kk) {
      constexpr int k = Kk.value;
      float v = 0.f;
      sfor<d1>([&](auto I) {
        sfor<d2>([&](auto J) {
          constexpr float cgc = CG_ALL.v[off + (I.value * d2 + J.value) * dl + k];
          if constexpr (cgc != 0.0f) {
            constexpr int ia = AOFFc[l1] + I.value, ja = AOFFc[l2] + J.value;
            constexpr int x = ia < ja ? ia : ja, y = ia < ja ? ja : ia;
            v = fmaf(cgc, A[x] * A[y], v);
          }
        });
      });
      B[lo + k] = fmaf(w, v, B[lo + k]);
    });
  });

  // ---- order 3
  sfor<18>([&](auto T) {
    constexpr int t   = T.value;
    constexpr int l1  = K_L1c[t], l2 = K_L2c[t], l12 = K_L12c[t];
    constexpr int d1  = 2 * l1 + 1, d2 = 2 * l2 + 1, d12 = 2 * l12 + 1;
    constexpr int off = T_OFFc[t];
    float tt[d12];
    sfor<d12>([&](auto Kk) {
      constexpr int k = Kk.value;
      float v = 0.f;
      sfor<d1>([&](auto I) {
        sfor<d2>([&](auto J) {
          constexpr float cgc = CG_ALL.v[off + (I.value * d2 + J.value) * d12 + k];
          if constexpr (cgc != 0.0f) {
            constexpr int ia = AOFFc[l1] + I.value, ja = AOFFc[l2] + J.value;
            constexpr int x = ia < ja ? ia : ja, y = ia < ja ? ja : ia;
            v = fmaf(cgc, A[x] * A[y], v);
          }
        });
      });
      tt[k] = v;
    });
    constexpr int pcnt = P3_STARTc[t + 1] - P3_STARTc[t];
    sfor<pcnt>([&](auto PP) {
      constexpr int p  = P3_STARTc[t] + PP.value;
      constexpr int l3 = P3_L3c[p], lo = P3_LOc[p];
      constexpr int d3 = 2 * l3 + 1, dl = 2 * lo + 1;
      constexpr int off2 = T_OFFc[P3_TBLc[p]];
      const float w = w3p[p * NC];
      sfor<dl>([&](auto M) {
        float v = 0.f;
        sfor<d12>([&](auto Kk) {
          sfor<d3>([&](auto J) {
            constexpr float cgc = CG_ALL.v[off2 + (Kk.value * d3 + J.value) * dl + M.value];
            if constexpr (cgc != 0.0f)
              v = fmaf(cgc, tt[Kk.value] * A[AOFFc[l3] + J.value], v);
          });
        });
        B[lo + M.value] = fmaf(w, v, B[lo + M.value]);
      });
    });
  });
}

// ------------------------------- main kernel -----------------------------------
__global__ __launch_bounds__(256) void epb_main(
    const float* __restrict__ nf,      // [N, C, 9]
    const float* __restrict__ w1,      // [E, 2, C]
    const float* __restrict__ w2,      // [E, 9, C]
    const float* __restrict__ w3,      // [E, 51, C]
    const float* __restrict__ lw0,     // [C, F=128]
    const float* __restrict__ lw1,     // [C, F=128]
    const int*   __restrict__ species, // [N]
    float* __restrict__ out)           // [N, F, 4]
{
  __shared__ float  Anf[TN * NC * 9];  // 36 KB
  __shared__ float4 Bsh[TN * NC];      // 16 KB  [node][channel]
  const int t  = threadIdx.x;
  const int nb = blockIdx.x * TN;

  // ---- stage node_feats tile (coalesced float4)
  {
    const float4* src = reinterpret_cast<const float4*>(nf + (size_t)nb * (NC * 9));
    float4* dst = reinterpret_cast<float4*>(Anf);
    #pragma unroll
    for (int i = 0; i < 9; ++i) dst[t + 256 * i] = src[t + 256 * i];
  }
  __syncthreads();

  // ---- basis: 4 (node,channel) pairs per thread
  {
    const int c = t & 127, h = t >> 7;
    #pragma unroll 1
    for (int q = 0; q < 4; ++q) {
      const int nl = h + 2 * q;
      const int s  = species[nb + nl];
      const float* w1p = w1 + (size_t)s * 2  * NC + c;
      const float* w2p = w2 + (size_t)s * 9  * NC + c;
      const float* w3p = w3 + (size_t)s * 51 * NC + c;
      float B[4];
      basis_pair(Anf + nl * (NC * 9) + c * 9, w1p, w2p, w3p, B);
      Bsh[nl * NC + c] = make_float4(B[0], B[1], B[2], B[3]);
    }
  }
  __syncthreads();

  // ---- linear: 2 features x 2 nodes per thread
  const int fl = t & 63, g = t >> 6;   // nodes g and g+4; features fl and fl+64
  const float* pa = lw0 + fl;
  const float* pb = lw1 + fl;
  const float4* b0p = &Bsh[g * NC];
  const float4* b1p = &Bsh[(g + 4) * NC];

  float a00 = 0.f, a01 = 0.f, a02 = 0.f, a03 = 0.f;   // node g,   f=fl
  float a10 = 0.f, a11 = 0.f, a12 = 0.f, a13 = 0.f;   // node g,   f=fl+64
  float a20 = 0.f, a21 = 0.f, a22 = 0.f, a23 = 0.f;   // node g+4, f=fl
  float a30 = 0.f, a31 = 0.f, a32 = 0.f, a33 = 0.f;   // node g+4, f=fl+64

  #pragma unroll 8
  for (int ch = 0; ch < NC; ++ch) {
    const float wa0 = pa[ch * NC];
    const float wa1 = pa[ch * NC + 64];
    const float wb0 = pb[ch * NC];
    const float wb1 = pb[ch * NC + 64];
    const float4 b0 = b0p[ch];   // wave-uniform -> LDS broadcast
    const float4 b1 = b1p[ch];
    a00 = fmaf(b0.x, wa0, a00); a01 = fmaf(b0.y, wb0, a01);
    a02 = fmaf(b0.z, wb0, a02); a03 = fmaf(b0.w, wb0, a03);
    a10 = fmaf(b0.x, wa1, a10); a11 = fmaf(b0.y, wb1, a11);
    a12 = fmaf(b0.z, wb1, a12); a13 = fmaf(b0.w, wb1, a13);
    a20 = fmaf(b1.x, wa0, a20); a21 = fmaf(b1.y, wb0, a21);
    a22 = fmaf(b1.z, wb0, a22); a23 = fmaf(b1.w, wb0, a23);
    a30 = fmaf(b1.x, wa1, a30); a31 = fmaf(b1.y, wb1, a31);
    a32 = fmaf(b1.z, wb1, a32); a33 = fmaf(b1.w, wb1, a33);
  }

  const float s4 = 0.08838834764831845f;  // 1/sqrt(128)
  float4* out4 = reinterpret_cast<float4*>(out);
  out4[(size_t)(nb + g) * NC + fl]          = make_float4(a00*s4, a01*s4, a02*s4, a03*s4);
  out4[(size_t)(nb + g) * NC + fl + 64]     = make_float4(a10*s4, a11*s4, a12*s4, a13*s4);
  out4[(size_t)(nb + g + 4) * NC + fl]      = make_float4(a20*s4, a21*s4, a22*s4, a23*s4);
  out4[(size_t)(nb + g + 4) * NC + fl + 64] = make_float4(a30*s4, a31*s4, a32*s4, a33*s4);
}

// ------------------------------- launcher --------------------------------------
extern "C" void kernel_launch(void* const* d_in, const int* in_sizes, int n_in,
                              void* d_out, int out_size, void* d_ws, size_t ws_size,
                              hipStream_t stream) {
  const float* nf  = (const float*)d_in[0];
  const float* w1  = (const float*)d_in[1];
  const float* w2  = (const float*)d_in[2];
  const float* w3  = (const float*)d_in[3];
  const float* lw0 = (const float*)d_in[4];
  const float* lw1 = (const float*)d_in[5];
  const int*   spc = (const int*)  d_in[6];
  float* out = (float*)d_out;
  (void)d_ws; (void)ws_size; (void)in_sizes; (void)n_in; (void)out_size;

  hipLaunchKernelGGL(epb_main, dim3(NN / TN), dim3(256), 0, stream,
                     nf, w1, w2, w3, lw0, lw1, spc, out);
}